// Round 3
// baseline (858.420 us; speedup 1.0000x reference)
//
#include <hip/hip_runtime.h>
#include <hip/hip_bf16.h>
#include <math.h>

// Problem constants
#define NN 32768          // Dd*Hh*Ww tokens per batch
#define CC 256
#define EE 6
#define HID 1024
#define TT 64             // tokens per workgroup
#define NTOK 65536        // B * NN

typedef __attribute__((ext_vector_type(8))) short bf16x8;   // 8 bf16 = 4 VGPRs
typedef __attribute__((ext_vector_type(4))) float f32x4;
typedef __attribute__((ext_vector_type(4))) unsigned int u32x4;
typedef __attribute__((ext_vector_type(2))) unsigned int u32x2;

__device__ __forceinline__ unsigned short f32_bf16(float f) {
  unsigned u = __builtin_bit_cast(unsigned, f);
  u += 0x7FFFu + ((u >> 16) & 1u);          // RNE
  return (unsigned short)(u >> 16);
}

// tanh-form GELU via sigmoid identity; max abs dev from erf-GELU ~1e-3.
__device__ __forceinline__ float fast_gelu(float v) {
  float s = v * v;
  float a = v * -2.3021181819f;
  float m = a * 0.044715f;
  float nu = __builtin_fmaf(m, s, a);       // -(2u*log2e)
  float z = __builtin_amdgcn_exp2f(nu);
  return v * __builtin_amdgcn_rcpf(1.0f + z);
}

// one-time f32 -> bf16 weight conversion into workspace
__global__ void wconv(const float* __restrict__ w1, const float* __restrict__ w2,
                      unsigned short* __restrict__ w1b, unsigned short* __restrict__ w2b) {
  int i = blockIdx.x * 256 + threadIdx.x;
  w1b[i] = f32_bf16(w1[i]);
  w2b[i] = f32_bf16(w2[i]);
}

// Pipelined swapped-operand design, one barrier per 128-wide HID chunk:
//   phase k: [issue w1 loads for GEMM1(k)] -> GEMM2(k-1) from hs[(k-1)&1]
//            -> GEMM1(k) MFMA -> GELU -> write hs[k&1] -> barrier
// GEMM1: Hd^T[h 128][t 64] (wave owns 32 h); GEMM2: O^T[c 256][t 64] (wave owns 64 c).
__global__ __launch_bounds__(256, 2) void moe_main(
    const float* __restrict__ x, const float* __restrict__ attn,
    const float* __restrict__ gate_w, const float* __restrict__ gate_b,
    const float* __restrict__ b1, const float* __restrict__ b2,
    const unsigned short* __restrict__ w1b, const unsigned short* __restrict__ w2b,
    float* __restrict__ out) {
  __shared__ unsigned char xs[TT * CC * 2];        // 32 KB  X tile [t][c], swizzled
  __shared__ unsigned char hs[2][TT * 128 * 2];    // 2x16 KB Hd chunk [t][h''], swizzled
  __shared__ float gwS[EE * CC];                   // 6 KB
  __shared__ float maskS[EE * TT];                 // 1.5 KB

  const int tid  = threadIdx.x;
  const int lane = tid & 63;
  const int wv   = tid >> 6;        // wave id 0..3
  const int lr   = lane & 15;
  const int lg   = lane >> 4;

  const int token0 = blockIdx.x * TT;
  const int bIdx   = token0 >> 15;          // batch (NN = 32768)
  const int n0     = token0 & (NN - 1);

  for (int i = tid; i < EE * CC; i += 256) gwS[i] = gate_w[i];
  __syncthreads();

  // ---------- stage X (f32 -> bf16, [t][c] rows, swizzled) + gate partials ----------
  float* gred = (float*)hs;   // [4][64][6] partial gate sums (hs free here)
  {
    float gp[EE] = {0.f, 0.f, 0.f, 0.f, 0.f, 0.f};
    const int t = lane;
    const unsigned trow = (unsigned)t * 512u;
    const unsigned tsw  = ((unsigned)(t & 31)) << 4;
    const size_t xbase = ((size_t)bIdx * CC + wv * 64) * NN + n0 + lane;
    #pragma unroll 1
    for (int c8 = 0; c8 < 8; ++c8) {
      float xv[8];
      #pragma unroll
      for (int j = 0; j < 8; ++j)
        xv[j] = x[xbase + (size_t)(c8 * 8 + j) * NN];   // coalesced over lanes
      #pragma unroll
      for (int j = 0; j < 8; ++j) {
        int c = wv * 64 + c8 * 8 + j;
        #pragma unroll
        for (int e = 0; e < EE; ++e) gp[e] = __builtin_fmaf(xv[j], gwS[e * CC + c], gp[e]);
      }
      u32x4 pk;
      #pragma unroll
      for (int q = 0; q < 4; ++q)
        pk[q] = (unsigned)f32_bf16(xv[2 * q]) | ((unsigned)f32_bf16(xv[2 * q + 1]) << 16);
      unsigned byteo = trow + (((unsigned)((wv * 64 + c8 * 8) * 2)) ^ tsw);
      *(u32x4*)(xs + byteo) = pk;
    }
    #pragma unroll
    for (int e = 0; e < EE; ++e) gred[(wv * 64 + lane) * EE + e] = gp[e];
  }
  __syncthreads();

  // ---------- gating: f32 softmax + top-3 (selection on exact logits) ----------
  if (tid < 64) {
    float g[EE];
    #pragma unroll
    for (int e = 0; e < EE; ++e)
      g[e] = gred[(0 * 64 + tid) * EE + e] + gred[(1 * 64 + tid) * EE + e] +
             gred[(2 * 64 + tid) * EE + e] + gred[(3 * 64 + tid) * EE + e];
    float aw = attn[token0 + tid];
    float m = -1e30f;
    #pragma unroll
    for (int e = 0; e < EE; ++e) { g[e] = (g[e] + gate_b[e]) * aw; m = fmaxf(m, g[e]); }
    float ex[EE], s = 0.f;
    #pragma unroll
    for (int e = 0; e < EE; ++e) { ex[e] = expf(g[e] - m); s += ex[e]; }
    int i1 = 0; float v1 = g[0];
    #pragma unroll
    for (int e = 1; e < EE; ++e) if (g[e] > v1) { v1 = g[e]; i1 = e; }
    int i2 = -1; float v2 = -3.4e38f;
    #pragma unroll
    for (int e = 0; e < EE; ++e) if (e != i1 && g[e] > v2) { v2 = g[e]; i2 = e; }
    int i3 = -1; float v3 = -3.4e38f;
    #pragma unroll
    for (int e = 0; e < EE; ++e) if (e != i1 && e != i2 && g[e] > v3) { v3 = g[e]; i3 = e; }
    float inv = 1.f / s;
    #pragma unroll
    for (int e = 0; e < EE; ++e)
      maskS[e * TT + tid] = (e == i1 || e == i2 || e == i3) ? ex[e] * inv : 0.f;
  }
  __syncthreads();

  // ---------- main pipelined loop over 48 chunks (6 experts x 8 x 128 h) ----------
  f32x4 oacc[4][4];   // O^T accum: c = wv*64+fm*16+lg*4+r, t = fn*16+lr
  #pragma unroll
  for (int fm = 0; fm < 4; ++fm)
    #pragma unroll
    for (int fn = 0; fn < 4; ++fn) oacc[fm][fn] = (f32x4){0.f, 0.f, 0.f, 0.f};

  unsigned trowX[4], tswX[4], trowH[4], tswH[4];
  #pragma unroll
  for (int fn = 0; fn < 4; ++fn) {
    int t = fn * 16 + lr;
    trowX[fn] = (unsigned)t * 512u;
    tswX[fn]  = ((unsigned)(t & 31)) << 4;
    trowH[fn] = (unsigned)t * 256u;
    tswH[fn]  = ((unsigned)(t & 15)) << 4;
  }

  #pragma unroll 1
  for (int k = 0; k < 48; ++k) {
    const int e  = k >> 3;
    const int kc = k & 7;

    // ---- issue w1 loads for GEMM1(k): 16 x dwordx4, latency hides under GEMM2 ----
    bf16x8 af[8][2];
    {
      const unsigned short* w1p =
          w1b + ((size_t)(e * HID + kc * 128 + wv * 32 + lr)) * CC + lg * 8;
      #pragma unroll
      for (int ks = 0; ks < 8; ++ks)
        #pragma unroll
        for (int fm = 0; fm < 2; ++fm)
          af[ks][fm] = *(const bf16x8*)(w1p + fm * 16 * CC + ks * 32);
    }

    // ---- GEMM2 for previous chunk from hs[(k-1)&1] ----
    if (k > 0) {
      const int pe  = (k - 1) >> 3;
      const int pkc = (k - 1) & 7;
      const unsigned char* hb = hs[(k - 1) & 1];
      const unsigned short* w2p =
          w2b + ((size_t)(pe * CC + wv * 64 + lr)) * HID + pkc * 128 + lg * 8;
      #pragma unroll
      for (int ks2 = 0; ks2 < 4; ++ks2) {
        bf16x8 am[4], bh[4];
        #pragma unroll
        for (int fm = 0; fm < 4; ++fm)
          am[fm] = *(const bf16x8*)(w2p + fm * 16 * HID + ks2 * 32);
        #pragma unroll
        for (int fn = 0; fn < 4; ++fn)
          bh[fn] = *(const bf16x8*)(hb + trowH[fn] +
                                    (((unsigned)(ks2 * 64 + lg * 16)) ^ tswH[fn]));
        #pragma unroll
        for (int fn = 0; fn < 4; ++fn)
          #pragma unroll
          for (int fm = 0; fm < 4; ++fm)
            oacc[fm][fn] =
                __builtin_amdgcn_mfma_f32_16x16x32_bf16(am[fm], bh[fn], oacc[fm][fn], 0, 0, 0);
      }
    }

    // ---- GEMM1(k): Hd^T[32 h per wave][64 t], weights already in af ----
    f32x4 hacc[2][4];
    #pragma unroll
    for (int fm = 0; fm < 2; ++fm)
      #pragma unroll
      for (int fn = 0; fn < 4; ++fn) hacc[fm][fn] = (f32x4){0.f, 0.f, 0.f, 0.f};
    #pragma unroll
    for (int ks = 0; ks < 8; ++ks) {
      bf16x8 bx[4];
      #pragma unroll
      for (int fn = 0; fn < 4; ++fn)
        bx[fn] = *(const bf16x8*)(xs + trowX[fn] +
                                  (((unsigned)(ks * 64 + lg * 16)) ^ tswX[fn]));
      #pragma unroll
      for (int fn = 0; fn < 4; ++fn)
        #pragma unroll
        for (int fm = 0; fm < 2; ++fm)
          hacc[fm][fn] =
              __builtin_amdgcn_mfma_f32_16x16x32_bf16(af[ks][fm], bx[fn], hacc[fm][fn], 0, 0, 0);
    }

    // ---- bias + GELU + mask, packed b64 writes into hs[k&1] ----
    {
      f32x4 b1v[2];
      #pragma unroll
      for (int fm = 0; fm < 2; ++fm)
        b1v[fm] = *(const f32x4*)&b1[e * HID + kc * 128 + wv * 32 + fm * 16 + lg * 4];
      unsigned char* hw = hs[k & 1];
      #pragma unroll
      for (int fn = 0; fn < 4; ++fn) {
        float msk = maskS[e * TT + fn * 16 + lr];
        #pragma unroll
        for (int fm = 0; fm < 2; ++fm) {
          float gg[4];
          #pragma unroll
          for (int r = 0; r < 4; ++r)
            gg[r] = fast_gelu(hacc[fm][fn][r] + b1v[fm][r]) * msk;
          u32x2 pk;
          pk[0] = (unsigned)f32_bf16(gg[0]) | ((unsigned)f32_bf16(gg[1]) << 16);
          pk[1] = (unsigned)f32_bf16(gg[2]) | ((unsigned)f32_bf16(gg[3]) << 16);
          unsigned byteo = trowH[fn] +
              (((unsigned)(wv * 64 + fm * 32 + lg * 8)) ^ tswH[fn]);
          *(u32x2*)(hw + byteo) = pk;
        }
      }
    }
    __syncthreads();
  }

  // ---- final GEMM2 for chunk 47 from hs[1] ----
  {
    const unsigned char* hb = hs[1];
    const unsigned short* w2p =
        w2b + ((size_t)(5 * CC + wv * 64 + lr)) * HID + 7 * 128 + lg * 8;
    #pragma unroll
    for (int ks2 = 0; ks2 < 4; ++ks2) {
      bf16x8 am[4], bh[4];
      #pragma unroll
      for (int fm = 0; fm < 4; ++fm)
        am[fm] = *(const bf16x8*)(w2p + fm * 16 * HID + ks2 * 32);
      #pragma unroll
      for (int fn = 0; fn < 4; ++fn)
        bh[fn] = *(const bf16x8*)(hb + trowH[fn] +
                                  (((unsigned)(ks2 * 64 + lg * 16)) ^ tswH[fn]));
      #pragma unroll
      for (int fn = 0; fn < 4; ++fn)
        #pragma unroll
        for (int fm = 0; fm < 4; ++fm)
          oacc[fm][fn] =
              __builtin_amdgcn_mfma_f32_16x16x32_bf16(am[fm], bh[fn], oacc[fm][fn], 0, 0, 0);
    }
  }

  // ---------- epilogue: += sum_e mask[e][t] * b2[e][c], then store ----------
  #pragma unroll
  for (int e = 0; e < EE; ++e) {
    float msk[4];
    #pragma unroll
    for (int fn = 0; fn < 4; ++fn) msk[fn] = maskS[e * TT + fn * 16 + lr];
    #pragma unroll
    for (int fm = 0; fm < 4; ++fm) {
      f32x4 b2v = *(const f32x4*)&b2[e * CC + wv * 64 + fm * 16 + lg * 4];
      #pragma unroll
      for (int fn = 0; fn < 4; ++fn)
        #pragma unroll
        for (int r = 0; r < 4; ++r)
          oacc[fm][fn][r] = __builtin_fmaf(msk[fn], b2v[r], oacc[fm][fn][r]);
    }
  }
  const size_t obase = ((size_t)bIdx * CC) * NN + n0;
  #pragma unroll
  for (int fm = 0; fm < 4; ++fm) {
    #pragma unroll
    for (int fn = 0; fn < 4; ++fn) {
      int t = fn * 16 + lr;
      #pragma unroll
      for (int r = 0; r < 4; ++r) {
        int c = wv * 64 + fm * 16 + lg * 4 + r;
        out[obase + (size_t)c * NN + t] = oacc[fm][fn][r];
      }
    }
  }
}

extern "C" void kernel_launch(void* const* d_in, const int* in_sizes, int n_in,
                              void* d_out, int out_size, void* d_ws, size_t ws_size,
                              hipStream_t stream) {
  const float* x      = (const float*)d_in[0];
  const float* attn   = (const float*)d_in[1];
  const float* gate_w = (const float*)d_in[2];
  const float* gate_b = (const float*)d_in[3];
  const float* w1     = (const float*)d_in[4];
  const float* b1     = (const float*)d_in[5];
  const float* w2     = (const float*)d_in[6];
  const float* b2     = (const float*)d_in[7];
  float* out = (float*)d_out;

  unsigned short* w1b = (unsigned short*)d_ws;                  // 3 MB
  unsigned short* w2b = w1b + (size_t)EE * HID * CC;            // 3 MB

  wconv<<<(EE * HID * CC) / 256, 256, 0, stream>>>(w1, w2, w1b, w2b);
  moe_main<<<NTOK / TT, 256, 0, stream>>>(x, attn, gate_w, gate_b, b1, b2, w1b, w2b, out);
}